// Round 2
// baseline (18058.826 us; speedup 1.0000x reference)
//
#include <hip/hip_runtime.h>
#include <math.h>

// Problem constants (fixed by setup_inputs)
constexpr int U      = 128;   // UNITS
constexpr int G4     = 512;   // 4*U gate width
constexpr int NC     = 10;    // classes
constexpr int TSTEPS = 1000;
constexpr int BATCH  = 256;

__device__ __forceinline__ float sigm(float x) {
    return 1.0f / (1.0f + __expf(-x));
}

// matches jnp.mod (floor-mod) semantics: fmod exact, then sign-adjust
__device__ __forceinline__ float tgate(float t, float tau, float s) {
    float r = fmodf(t - s, tau);
    if (r < 0.0f) r += tau;
    float phi = r / tau;
    if (phi < 0.025f) return 40.0f * phi;        // 2*phi/R_ON
    if (phi < 0.05f)  return 2.0f - 40.0f * phi; // 2 - 2*phi/R_ON
    return 0.001f * phi;                          // ALPHA*phi
}

__device__ __forceinline__ float4 f4ma(float s, float4 a, float4 acc) {
    acc.x += s * a.x; acc.y += s * a.y; acc.z += s * a.z; acc.w += s * a.w;
    return acc;
}

// One workgroup per batch element, 512 threads = 8 waves.
// Thread tid: g = tid>>7 (K-quarter, wave-pair uniform), l = tid&127,
// owns output columns 4l..4l+3 and K-range [32g, 32g+32).
// Weight loads are global_load_dwordx4 from the native row-major layout
// (consecutive lanes -> consecutive 16B), and Wh0 (full slice) + 12/32 of
// Wx1's slice live in registers for the whole kernel.
__global__ __launch_bounds__(512) void plstm_fused(
    const float* __restrict__ inputs,  // [B,T,3]
    const float* __restrict__ times,   // [B,T]
    const float* __restrict__ Wx0,     // [3,512]
    const float* __restrict__ Wh0,     // [128,512]
    const float* __restrict__ b0,      // [512]
    const float* __restrict__ tau0,    // [128]
    const float* __restrict__ s0,      // [128]
    const float* __restrict__ Wx1,     // [128,512]
    const float* __restrict__ Wh1,     // [128,512]
    const float* __restrict__ b1,      // [512]
    const float* __restrict__ tau1,    // [128]
    const float* __restrict__ s1,      // [128]
    const float* __restrict__ gamma_,  // [128]
    const float* __restrict__ beta_,   // [128]
    const float* __restrict__ Wfc,     // [128,10]
    const float* __restrict__ bfc,     // [10]
    float* __restrict__ out)           // [B,T,10]
{
    const int b   = blockIdx.x;
    const int tid = threadIdx.x;
    const int g   = tid >> 7;        // 0..3  (wave-pair uniform)
    const int l   = tid & 127;       // 0..127
    const int kbase = 32 * g;
    const int cbase = 4 * l;

    __shared__ __align__(16) float h0s[U];
    __shared__ __align__(16) float h1s[U];
    __shared__ __align__(16) float hns[U];
    __shared__ __align__(16) float zs4[4 * G4];   // split-K partials [g][col]
    __shared__ float WfcL[U * NC];
    __shared__ float bfcL[NC];
    __shared__ float red[2];   // mu, rstd

    // ---- register-cached weights (loop-invariant) ----
    float4 wh0c[32];                 // full Wh0 slice: 128 VGPRs
    #pragma unroll
    for (int kk = 0; kk < 32; ++kk)
        wh0c[kk] = *reinterpret_cast<const float4*>(&Wh0[(kbase + kk) * G4 + cbase]);
    constexpr int WX1C = 12;         // cached Wx1 rows of the 32-slice: 48 VGPRs
    float4 wx1c[WX1C];
    #pragma unroll
    for (int kk = 0; kk < WX1C; ++kk)
        wx1c[kk] = *reinterpret_cast<const float4*>(&Wx1[(kbase + kk) * G4 + cbase]);

    // g==0 threads fold bias + x@Wx0 into their partial
    float4 b0v = {0,0,0,0}, b1v = {0,0,0,0};
    float4 wx0a = {0,0,0,0}, wx0b = {0,0,0,0}, wx0c = {0,0,0,0};
    if (g == 0) {
        b0v  = *reinterpret_cast<const float4*>(&b0[cbase]);
        b1v  = *reinterpret_cast<const float4*>(&b1[cbase]);
        wx0a = *reinterpret_cast<const float4*>(&Wx0[cbase]);
        wx0b = *reinterpret_cast<const float4*>(&Wx0[G4 + cbase]);
        wx0c = *reinterpret_cast<const float4*>(&Wx0[2 * G4 + cbase]);
    }

    // per-unit state in registers (tid<128 owns unit tid)
    float tau0r = 0.f, s0r = 0.f, tau1r = 0.f, s1r = 0.f, gr = 0.f, br = 0.f;
    float c0r = 0.f, c1r = 0.f, h0r = 0.f, h1r = 0.f;
    if (tid < U) {
        tau0r = tau0[tid]; s0r = s0[tid];
        tau1r = tau1[tid]; s1r = s1[tid];
        gr = gamma_[tid];  br = beta_[tid];
        h0s[tid] = 0.0f;   h1s[tid] = 0.0f;
    }
    for (int i = tid; i < U * NC; i += 512) WfcL[i] = Wfc[i];
    if (tid < NC) bfcL[tid] = bfc[tid];
    __syncthreads();

    const float* xp = inputs + (size_t)b * TSTEPS * 3;
    const float* tp = times  + (size_t)b * TSTEPS;
    float*       op = out    + (size_t)b * TSTEPS * NC;

    for (int t = 0; t < TSTEPS; ++t) {
        const float x0 = xp[3 * t + 0];
        const float x1 = xp[3 * t + 1];
        const float x2 = xp[3 * t + 2];
        const float tv = tp[t];

        // ---- layer 0 partial: columns cbase..+3 over K-quarter (registers only)
        float4 acc = {0,0,0,0};
        if (g == 0) {
            acc = b0v;
            acc = f4ma(x0, wx0a, acc);
            acc = f4ma(x1, wx0b, acc);
            acc = f4ma(x2, wx0c, acc);
        }
        #pragma unroll
        for (int q = 0; q < 8; ++q) {
            const float4 h4 = *reinterpret_cast<const float4*>(&h0s[kbase + 4 * q]);
            acc = f4ma(h4.x, wh0c[4 * q + 0], acc);
            acc = f4ma(h4.y, wh0c[4 * q + 1], acc);
            acc = f4ma(h4.z, wh0c[4 * q + 2], acc);
            acc = f4ma(h4.w, wh0c[4 * q + 3], acc);
        }
        *reinterpret_cast<float4*>(&zs4[g * G4 + cbase]) = acc;
        __syncthreads();

        // ---- layer 0 gates + state update (unit threads)
        if (tid < U) {
            float zi = 0.f, zf = 0.f, zg = 0.f, zo = 0.f;
            #pragma unroll
            for (int gg2 = 0; gg2 < 4; ++gg2) {
                zi += zs4[gg2 * G4 + tid];
                zf += zs4[gg2 * G4 + tid + U];
                zg += zs4[gg2 * G4 + tid + 2 * U];
                zo += zs4[gg2 * G4 + tid + 3 * U];
            }
            const float ig = sigm(zi);
            const float fg = sigm(zf);
            const float gv = tanhf(zg);
            const float og = sigm(zo);
            const float ch = fg * c0r + ig * gv;
            const float hh = og * tanhf(ch);
            const float k  = tgate(tv, tau0r, s0r);
            h0r = k * hh + (1.0f - k) * h0r;
            c0r = k * ch + (1.0f - k) * c0r;
            h0s[tid] = h0r;
        }
        __syncthreads();

        // ---- LayerNorm stats (wave 0), two-pass variance
        if (tid < 64) {
            const float a  = h0s[tid];
            const float bv = h0s[tid + 64];
            float ssum = a + bv;
            #pragma unroll
            for (int off = 1; off < 64; off <<= 1) ssum += __shfl_xor(ssum, off);
            const float mu = ssum * (1.0f / 128.0f);
            const float da = a - mu, db = bv - mu;
            float vsum = da * da + db * db;
            #pragma unroll
            for (int off = 1; off < 64; off <<= 1) vsum += __shfl_xor(vsum, off);
            const float rstd = rsqrtf(vsum * (1.0f / 128.0f) + 1e-3f);
            if (tid == 0) { red[0] = mu; red[1] = rstd; }
        }
        __syncthreads();
        if (tid < U) {
            hns[tid] = gr * (h0r - red[0]) * red[1] + br;
        }
        __syncthreads();

        // ---- layer 1 partial: hn@Wx1 + h1@Wh1 over K-quarter
        float4 acc1 = {0,0,0,0};
        if (g == 0) acc1 = b1v;
        #pragma unroll
        for (int q = 0; q < 8; ++q) {
            const float4 hn4 = *reinterpret_cast<const float4*>(&hns[kbase + 4 * q]);
            const float4 h14 = *reinterpret_cast<const float4*>(&h1s[kbase + 4 * q]);
            #pragma unroll
            for (int i = 0; i < 4; ++i) {
                const int kk = 4 * q + i;
                float4 wx;
                if (kk < WX1C) wx = wx1c[kk];   // compile-time after unroll
                else wx = *reinterpret_cast<const float4*>(&Wx1[(kbase + kk) * G4 + cbase]);
                const float4 wh = *reinterpret_cast<const float4*>(&Wh1[(kbase + kk) * G4 + cbase]);
                const float hnv = (i == 0) ? hn4.x : (i == 1) ? hn4.y : (i == 2) ? hn4.z : hn4.w;
                const float h1v = (i == 0) ? h14.x : (i == 1) ? h14.y : (i == 2) ? h14.z : h14.w;
                acc1 = f4ma(hnv, wx, acc1);
                acc1 = f4ma(h1v, wh, acc1);
            }
        }
        *reinterpret_cast<float4*>(&zs4[g * G4 + cbase]) = acc1;
        __syncthreads();

        // ---- layer 1 gates + state update
        if (tid < U) {
            float zi = 0.f, zf = 0.f, zg = 0.f, zo = 0.f;
            #pragma unroll
            for (int gg2 = 0; gg2 < 4; ++gg2) {
                zi += zs4[gg2 * G4 + tid];
                zf += zs4[gg2 * G4 + tid + U];
                zg += zs4[gg2 * G4 + tid + 2 * U];
                zo += zs4[gg2 * G4 + tid + 3 * U];
            }
            const float ig = sigm(zi);
            const float fg = sigm(zf);
            const float gv = tanhf(zg);
            const float og = sigm(zo);
            const float ch = fg * c1r + ig * gv;
            const float hh = og * tanhf(ch);
            const float k  = tgate(tv, tau1r, s1r);
            h1r = k * hh + (1.0f - k) * h1r;
            c1r = k * ch + (1.0f - k) * c1r;
            h1s[tid] = h1r;
        }
        __syncthreads();

        // ---- FC + softmax (wave 0); Wfc from LDS to save persistent VGPRs
        if (tid < 64) {
            const float a  = h1s[tid];
            const float bv = h1s[tid + 64];
            float p[NC];
            #pragma unroll
            for (int c = 0; c < NC; ++c)
                p[c] = a * WfcL[tid * NC + c] + bv * WfcL[(tid + 64) * NC + c];
            #pragma unroll
            for (int off = 1; off < 64; off <<= 1) {
                #pragma unroll
                for (int c = 0; c < NC; ++c) p[c] += __shfl_xor(p[c], off);
            }
            float m = -1e30f;
            #pragma unroll
            for (int c = 0; c < NC; ++c) { p[c] += bfcL[c]; m = fmaxf(m, p[c]); }
            float ss = 0.0f;
            #pragma unroll
            for (int c = 0; c < NC; ++c) { p[c] = __expf(p[c] - m); ss += p[c]; }
            const float inv = 1.0f / ss;
            if (tid < NC) op[t * NC + tid] = p[tid] * inv;
        }
        // zs4 write-after-read for next step is fenced by the barrier after
        // the layer-1 gate phase; FC touches only h1s/WfcL. No extra sync.
    }
}

extern "C" void kernel_launch(void* const* d_in, const int* in_sizes, int n_in,
                              void* d_out, int out_size, void* d_ws, size_t ws_size,
                              hipStream_t stream) {
    const float* inputs = (const float*)d_in[0];
    const float* times  = (const float*)d_in[1];
    const float* Wx0    = (const float*)d_in[2];
    const float* Wh0    = (const float*)d_in[3];
    const float* b0     = (const float*)d_in[4];
    const float* tau0   = (const float*)d_in[5];
    const float* s0     = (const float*)d_in[6];
    const float* Wx1    = (const float*)d_in[7];
    const float* Wh1    = (const float*)d_in[8];
    const float* b1     = (const float*)d_in[9];
    const float* tau1   = (const float*)d_in[10];
    const float* s1     = (const float*)d_in[11];
    const float* gamma_ = (const float*)d_in[12];
    const float* beta_  = (const float*)d_in[13];
    const float* Wfc    = (const float*)d_in[14];
    const float* bfc    = (const float*)d_in[15];
    float* out = (float*)d_out;

    dim3 grid(BATCH);
    dim3 block(512);
    hipLaunchKernelGGL(plstm_fused, grid, block, 0, stream,
                       inputs, times, Wx0, Wh0, b0, tau0, s0,
                       Wx1, Wh1, b1, tau1, s1, gamma_, beta_, Wfc, bfc, out);
}